// Round 4
// baseline (1150.062 us; speedup 1.0000x reference)
//
#include <hip/hip_runtime.h>

#define BN_EPS 1e-5f

__device__ __forceinline__ float lrelu(float x){ return x > 0.f ? x : 0.2f*x; }

// ---------------- CSR build (dst-sorted edge list) ----------------

__global__ __launch_bounds__(256) void hist_k(const int* __restrict__ dst,
                                              int* __restrict__ deg, int E){
  int e = blockIdx.x*256 + threadIdx.x;
  if (e < E) atomicAdd(&deg[dst[e]], 1);
}

__global__ __launch_bounds__(256) void scan1_k(int* __restrict__ degoff,
                                               int* __restrict__ bsum, int N){
  __shared__ int s[256];
  int t = threadIdx.x, i = blockIdx.x*256 + t;
  int v = (i < N) ? degoff[i] : 0;
  s[t] = v; __syncthreads();
  int x = v;
  for (int d = 1; d < 256; d <<= 1){
    int y = (t >= d) ? s[t-d] : 0;
    __syncthreads();
    x += y; s[t] = x;
    __syncthreads();
  }
  if (i < N) degoff[i] = x - v;          // block-local exclusive
  if (t == 255) bsum[blockIdx.x] = x;    // block total
}

__global__ __launch_bounds__(256) void scan2_k(int* __restrict__ bsum, int nb){
  __shared__ int s[256];
  int t = threadIdx.x;
  int v = (t < nb) ? bsum[t] : 0;
  s[t] = v; __syncthreads();
  int x = v;
  for (int d = 1; d < 256; d <<= 1){
    int y = (t >= d) ? s[t-d] : 0;
    __syncthreads();
    x += y; s[t] = x;
    __syncthreads();
  }
  if (t < nb) bsum[t] = x - v;           // exclusive block offsets
}

__global__ __launch_bounds__(256) void scan3_k(int* __restrict__ off,
                                               int* __restrict__ cursor,
                                               const int* __restrict__ bsum,
                                               int N, int E){
  int i = blockIdx.x*256 + threadIdx.x;
  if (i < N){
    int o = off[i] + bsum[blockIdx.x];
    off[i] = o; cursor[i] = o;
  }
  if (i == 0) off[N] = E;
}

__global__ __launch_bounds__(256) void scatter_k(const int* __restrict__ src,
                                                 const int* __restrict__ dst,
                                                 int* __restrict__ cursor,
                                                 int* __restrict__ srcs, int E){
  int e = blockIdx.x*256 + threadIdx.x;
  if (e < E){
    int p = atomicAdd(&cursor[dst[e]], 1);
    srcs[p] = src[e];
  }
}

// ---------------- GIN aggregation ----------------
__global__ __launch_bounds__(256) void agg_k(const float* __restrict__ hin,
                                             float* __restrict__ hout,
                                             const int* __restrict__ off,
                                             const int* __restrict__ srcs, int N){
  int node = blockIdx.x*8 + (threadIdx.x >> 5);
  int ln = threadIdx.x & 31;
  if (node >= N) return;
  const float* hp = hin + (size_t)node*96;
  float a0 = hp[ln], a1 = hp[ln+32], a2 = hp[ln+64];
  int jb = off[node], je = off[node+1];
  for (int j = jb; j < je; ++j){
    const float* q = hin + (size_t)srcs[j]*96;
    a0 += q[ln]; a1 += q[ln+32]; a2 += q[ln+64];
  }
  float* o = hout + (size_t)node*96;
  o[ln] = a0; o[ln+32] = a1; o[ln+64] = a2;
}

// ---------------- fused MLP, register-resident, one node per lane -------------
// h[96] + acc[96] in VGPRs; W1/W2/b/bn read via wave-uniform loads -> s_load
// (scalar pipe), so the VALU issues pure v_fmac_f32. No LDS, no barriers.
__global__ __launch_bounds__(256, 1) void mlp_reg_k(
    const float* __restrict__ hin, float* __restrict__ hout,
    const float* __restrict__ W1, const float* __restrict__ b1,
    const float* __restrict__ g, const float* __restrict__ beta,
    const float* __restrict__ mean, const float* __restrict__ var,
    const float* __restrict__ W2, const float* __restrict__ b2, int N)
{
  int node = blockIdx.x*256 + threadIdx.x;
  bool valid = node < N;
  int n = valid ? node : N-1;          // clamp: no OOB, tail lanes discarded

  float h[96];
  const float4* hp = (const float4*)(hin + (size_t)n*96);
  #pragma unroll
  for (int j = 0; j < 24; ++j){
    float4 v = hp[j];
    h[4*j] = v.x; h[4*j+1] = v.y; h[4*j+2] = v.z; h[4*j+3] = v.w;
  }

  float acc[96];
  #pragma unroll
  for (int d = 0; d < 96; ++d) acc[d] = b1[d];
  #pragma unroll
  for (int k = 0; k < 96; ++k){
    float hk = h[k];
    const float* wr = W1 + k*96;
    #pragma unroll
    for (int d = 0; d < 96; ++d) acc[d] = fmaf(hk, wr[d], acc[d]);
  }

  // mid = bn(lrelu(acc)) written back into h (h dead after GEMM1)
  #pragma unroll
  for (int d = 0; d < 96; ++d){
    float s = g[d] * rsqrtf(var[d] + BN_EPS);
    float m = lrelu(acc[d]);
    h[d] = (m - mean[d])*s + beta[d];
  }

  #pragma unroll
  for (int d = 0; d < 96; ++d) acc[d] = b2[d];
  #pragma unroll
  for (int k = 0; k < 96; ++k){
    float hk = h[k];
    const float* wr = W2 + k*96;
    #pragma unroll
    for (int d = 0; d < 96; ++d) acc[d] = fmaf(hk, wr[d], acc[d]);
  }

  if (valid){
    float4* op = (float4*)(hout + (size_t)node*96);
    #pragma unroll
    for (int j = 0; j < 24; ++j){
      float4 v;
      v.x = lrelu(acc[4*j]);   v.y = lrelu(acc[4*j+1]);
      v.z = lrelu(acc[4*j+2]); v.w = lrelu(acc[4*j+3]);
      op[j] = v;
    }
  }
}

// ---------------- pooling over sorted batch ----------------

__global__ __launch_bounds__(256) void bounds_k(const int* __restrict__ batch,
                                                int* __restrict__ go, int N, int G){
  int i = blockIdx.x*256 + threadIdx.x;
  if (i >= N) return;
  int b = batch[i];
  int prev = (i == 0) ? -1 : batch[i-1];
  for (int g = prev+1; g <= b; ++g) go[g] = i;
  if (i == N-1){
    for (int g = b+1; g <= G; ++g) go[g] = N;
  }
}

__global__ __launch_bounds__(128) void pool_k(const float* __restrict__ h,
                                              const int* __restrict__ go,
                                              float* __restrict__ pooled){
  int g = blockIdx.x, d = threadIdx.x;
  if (d >= 96) return;
  int nb = go[g], ne = go[g+1];
  float acc = 0.f;
  for (int n = nb; n < ne; ++n) acc += h[(size_t)n*96 + d];
  pooled[g*96 + d] = acc;
}

// ---------------- cond MLP + concat + BN + fc ----------------

__global__ __launch_bounds__(64) void final_k(
    const float* __restrict__ cond, const float* __restrict__ pooled,
    const float* __restrict__ cW1, const float* __restrict__ cb1,
    const float* __restrict__ cg, const float* __restrict__ cbeta,
    const float* __restrict__ cmean, const float* __restrict__ cvar,
    const float* __restrict__ cW2, const float* __restrict__ cb2,
    const float* __restrict__ bn_g, const float* __restrict__ bn_b,
    const float* __restrict__ bn_mean, const float* __restrict__ bn_var,
    const float* __restrict__ fcW, const float* __restrict__ fcb,
    float* __restrict__ out)
{
  int g = blockIdx.x, t = threadIdx.x;
  float cin[7];
  #pragma unroll
  for (int j = 0; j < 7; ++j) cin[j] = cond[g*7+j];
  float c1[5];
  #pragma unroll
  for (int i = 0; i < 5; ++i){
    float a = cb1[i];
    #pragma unroll
    for (int j = 0; j < 7; ++j) a = fmaf(cin[j], cW1[j*5+i], a);
    float s = cg[i] * rsqrtf(cvar[i] + BN_EPS);
    a = (a - cmean[i])*s + cbeta[i];
    c1[i] = a > 0.f ? a : 0.f;
  }
  float c2[5];
  #pragma unroll
  for (int i = 0; i < 5; ++i){
    float a = cb2[i];
    #pragma unroll
    for (int j = 0; j < 5; ++j) a = fmaf(c1[j], cW2[j*5+i], a);
    c2[i] = a > 0.f ? a : 0.f;
  }
  float acc = fcb[t];
  #pragma unroll
  for (int j = 0; j < 5; ++j){
    float s = bn_g[j] * rsqrtf(bn_var[j] + BN_EPS);
    float nb = (c2[j] - bn_mean[j])*s + bn_b[j];
    acc = fmaf(nb, fcW[j*64 + t], acc);
  }
  for (int j = 5; j < 101; ++j){
    float vj = pooled[g*96 + (j-5)];
    float s = bn_g[j] * rsqrtf(bn_var[j] + BN_EPS);
    float nb = (vj - bn_mean[j])*s + bn_b[j];
    acc = fmaf(nb, fcW[j*64 + t], acc);
  }
  out[g*64 + t] = acc;
}

// ---------------- launch ----------------

extern "C" void kernel_launch(void* const* d_in, const int* in_sizes, int n_in,
                              void* d_out, int out_size, void* d_ws, size_t ws_size,
                              hipStream_t stream)
{
  const float* x         = (const float*)d_in[0];
  const float* cond      = (const float*)d_in[1];
  const int*   ei        = (const int*)  d_in[2];
  const int*   batch     = (const int*)  d_in[3];
  const float* conv_W1   = (const float*)d_in[4];
  const float* conv_b1   = (const float*)d_in[5];
  const float* conv_g    = (const float*)d_in[6];
  const float* conv_beta = (const float*)d_in[7];
  const float* conv_mean = (const float*)d_in[8];
  const float* conv_var  = (const float*)d_in[9];
  const float* conv_W2   = (const float*)d_in[10];
  const float* conv_b2   = (const float*)d_in[11];
  const float* cW1       = (const float*)d_in[12];
  const float* cb1       = (const float*)d_in[13];
  const float* cg        = (const float*)d_in[14];
  const float* cbeta     = (const float*)d_in[15];
  const float* cmean     = (const float*)d_in[16];
  const float* cvar      = (const float*)d_in[17];
  const float* cW2       = (const float*)d_in[18];
  const float* cb2       = (const float*)d_in[19];
  const float* bn_g      = (const float*)d_in[20];
  const float* bn_b      = (const float*)d_in[21];
  const float* bn_mean   = (const float*)d_in[22];
  const float* bn_var    = (const float*)d_in[23];
  const float* fc_W      = (const float*)d_in[24];
  const float* fc_b      = (const float*)d_in[25];

  const int D = 96;
  int N = in_sizes[0] / D;
  int G = in_sizes[1] / 7;
  int E = in_sizes[2] / 2;
  const int* src = ei;
  const int* dst = ei + E;

  char* p = (char*)d_ws;
  auto carve = [&](size_t bytes)->void*{
    void* r = (void*)p; p += (bytes + 255) & ~(size_t)255; return r;
  };
  int*   off    = (int*)  carve((size_t)(N+1)*4);
  int*   cursor = (int*)  carve((size_t)N*4);
  int*   bsum   = (int*)  carve(256*4);
  int*   srcs   = (int*)  carve((size_t)E*4);
  int*   go     = (int*)  carve((size_t)(G+1)*4);
  float* pooled = (float*)carve((size_t)G*D*4);
  float* hA     = (float*)carve((size_t)N*D*4);
  float* hB     = (float*)carve((size_t)N*D*4);

  int gE = (E+255)/256, gN = (N+255)/256;

  hipMemsetAsync(off, 0, (size_t)(N+1)*4, stream);
  hist_k   <<<gE, 256, 0, stream>>>(dst, off, E);
  scan1_k  <<<gN, 256, 0, stream>>>(off, bsum, N);
  scan2_k  <<<1,  256, 0, stream>>>(bsum, gN);
  scan3_k  <<<gN, 256, 0, stream>>>(off, cursor, bsum, N, E);
  scatter_k<<<gE, 256, 0, stream>>>(src, dst, cursor, srcs, E);
  bounds_k <<<gN, 256, 0, stream>>>(batch, go, N, G);

  const float* hin = x;
  for (int l = 0; l < 3; ++l){
    agg_k<<<(N+7)/8, 256, 0, stream>>>(hin, hB, off, srcs, N);
    mlp_reg_k<<<(N+255)/256, 256, 0, stream>>>(hB, hA,
        conv_W1 + (size_t)l*D*D, conv_b1 + l*D,
        conv_g + l*D, conv_beta + l*D, conv_mean + l*D, conv_var + l*D,
        conv_W2 + (size_t)l*D*D, conv_b2 + l*D, N);
    hin = hA;
  }

  pool_k <<<G, 128, 0, stream>>>(hA, go, pooled);
  final_k<<<G, 64,  0, stream>>>(cond, pooled, cW1, cb1, cg, cbeta, cmean, cvar,
                                 cW2, cb2, bn_g, bn_b, bn_mean, bn_var,
                                 fc_W, fc_b, (float*)d_out);
}

// Round 5
// 563.653 us; speedup vs baseline: 2.0404x; 2.0404x over previous
//
#include <hip/hip_runtime.h>

#define BN_EPS 1e-5f

__device__ __forceinline__ float lrelu(float x){ return x > 0.f ? x : 0.2f*x; }

// ---------------- CSR build (dst-sorted edge list) ----------------

__global__ __launch_bounds__(256) void hist_k(const int* __restrict__ dst,
                                              int* __restrict__ deg, int E){
  int e = blockIdx.x*256 + threadIdx.x;
  if (e < E) atomicAdd(&deg[dst[e]], 1);
}

__global__ __launch_bounds__(256) void scan1_k(int* __restrict__ degoff,
                                               int* __restrict__ bsum, int N){
  __shared__ int s[256];
  int t = threadIdx.x, i = blockIdx.x*256 + t;
  int v = (i < N) ? degoff[i] : 0;
  s[t] = v; __syncthreads();
  int x = v;
  for (int d = 1; d < 256; d <<= 1){
    int y = (t >= d) ? s[t-d] : 0;
    __syncthreads();
    x += y; s[t] = x;
    __syncthreads();
  }
  if (i < N) degoff[i] = x - v;          // block-local exclusive
  if (t == 255) bsum[blockIdx.x] = x;    // block total
}

__global__ __launch_bounds__(256) void scan2_k(int* __restrict__ bsum, int nb){
  __shared__ int s[256];
  int t = threadIdx.x;
  int v = (t < nb) ? bsum[t] : 0;
  s[t] = v; __syncthreads();
  int x = v;
  for (int d = 1; d < 256; d <<= 1){
    int y = (t >= d) ? s[t-d] : 0;
    __syncthreads();
    x += y; s[t] = x;
    __syncthreads();
  }
  if (t < nb) bsum[t] = x - v;           // exclusive block offsets
}

__global__ __launch_bounds__(256) void scan3_k(int* __restrict__ off,
                                               int* __restrict__ cursor,
                                               const int* __restrict__ bsum,
                                               int N, int E){
  int i = blockIdx.x*256 + threadIdx.x;
  if (i < N){
    int o = off[i] + bsum[blockIdx.x];
    off[i] = o; cursor[i] = o;
  }
  if (i == 0) off[N] = E;
}

__global__ __launch_bounds__(256) void scatter_k(const int* __restrict__ src,
                                                 const int* __restrict__ dst,
                                                 int* __restrict__ cursor,
                                                 int* __restrict__ srcs, int E){
  int e = blockIdx.x*256 + threadIdx.x;
  if (e < E){
    int p = atomicAdd(&cursor[dst[e]], 1);
    srcs[p] = src[e];
  }
}

// ---------------- GIN aggregation ----------------
__global__ __launch_bounds__(256) void agg_k(const float* __restrict__ hin,
                                             float* __restrict__ hout,
                                             const int* __restrict__ off,
                                             const int* __restrict__ srcs, int N){
  int node = blockIdx.x*8 + (threadIdx.x >> 5);
  int ln = threadIdx.x & 31;
  if (node >= N) return;
  const float* hp = hin + (size_t)node*96;
  float a0 = hp[ln], a1 = hp[ln+32], a2 = hp[ln+64];
  int jb = off[node], je = off[node+1];
  for (int j = jb; j < je; ++j){
    const float* q = hin + (size_t)srcs[j]*96;
    a0 += q[ln]; a1 += q[ln+32]; a2 += q[ln+64];
  }
  float* o = hout + (size_t)node*96;
  o[ln] = a0; o[ln+32] = a1; o[ln+64] = a2;
}

// ---------------- fused MLP: wave-uniform weight slices -----------------------
// 8 waves/block; wave w owns dims d0=w*12 (uniform -> W via s_load, scalar
// pipe); lane = node (64-node tile). Per k-iter per wave: 1 ds_read_b32 +
// 12 v_fmac. h tile in LDS (pad 67 -> conflict-free), acc[12] in VGPRs.
__global__ __launch_bounds__(512) void mlp_sw_k(
    const float* __restrict__ hin, float* __restrict__ hout,
    const float* __restrict__ W1, const float* __restrict__ b1,
    const float* __restrict__ g, const float* __restrict__ beta,
    const float* __restrict__ mean, const float* __restrict__ var,
    const float* __restrict__ W2, const float* __restrict__ b2, int N)
{
  __shared__ float hT[96*67];          // [k][n] pad 67: bank=(3k+n)%32
  int t = threadIdx.x;
  int nbase = blockIdx.x * 64;
  int lim = (N - nbase) * 96;          // valid flat extent of this tile
  const float* hbase = hin + (size_t)nbase*96;

  #pragma unroll
  for (int i = 0; i < 12; ++i){        // coalesced stage-in, transpose in LDS
    int tid = t + 512*i;
    float v = (tid < lim) ? hbase[tid] : 0.f;
    int n = tid / 96, k = tid - n*96;
    hT[k*67 + n] = v;
  }
  __syncthreads();

  int ln = t & 63;
  int d0 = __builtin_amdgcn_readfirstlane((t >> 6) * 12);  // wave-uniform dims

  float acc[12];
  #pragma unroll
  for (int j = 0; j < 12; ++j) acc[j] = b1[d0+j];
  #pragma unroll 4
  for (int k = 0; k < 96; ++k){
    float hk = hT[k*67 + ln];
    const float* wr = W1 + k*96 + d0;  // uniform address -> s_load
    #pragma unroll
    for (int j = 0; j < 12; ++j) acc[j] = fmaf(hk, wr[j], acc[j]);
  }
  __syncthreads();                     // all GEMM1 reads done before overwrite

  #pragma unroll
  for (int j = 0; j < 12; ++j){        // mid = bn(lrelu(acc)) -> hT rows d0..
    int d = d0 + j;
    float s = g[d] * rsqrtf(var[d] + BN_EPS);
    float m = lrelu(acc[j]);
    hT[d*67 + ln] = (m - mean[d])*s + beta[d];
  }
  __syncthreads();

  #pragma unroll
  for (int j = 0; j < 12; ++j) acc[j] = b2[d0+j];
  #pragma unroll 4
  for (int k = 0; k < 96; ++k){
    float hk = hT[k*67 + ln];
    const float* wr = W2 + k*96 + d0;
    #pragma unroll
    for (int j = 0; j < 12; ++j) acc[j] = fmaf(hk, wr[j], acc[j]);
  }
  __syncthreads();                     // all GEMM2 reads done before overwrite

  #pragma unroll
  for (int j = 0; j < 12; ++j)
    hT[(d0+j)*67 + ln] = lrelu(acc[j]);
  __syncthreads();

  float* obase = hout + (size_t)nbase*96;
  #pragma unroll
  for (int i = 0; i < 12; ++i){        // transpose out, coalesced global write
    int tid = t + 512*i;
    int n = tid / 96, k = tid - n*96;
    if (tid < lim) obase[tid] = hT[k*67 + n];
  }
}

// ---------------- pooling over sorted batch ----------------

__global__ __launch_bounds__(256) void bounds_k(const int* __restrict__ batch,
                                                int* __restrict__ go, int N, int G){
  int i = blockIdx.x*256 + threadIdx.x;
  if (i >= N) return;
  int b = batch[i];
  int prev = (i == 0) ? -1 : batch[i-1];
  for (int g = prev+1; g <= b; ++g) go[g] = i;
  if (i == N-1){
    for (int g = b+1; g <= G; ++g) go[g] = N;
  }
}

__global__ __launch_bounds__(128) void pool_k(const float* __restrict__ h,
                                              const int* __restrict__ go,
                                              float* __restrict__ pooled){
  int g = blockIdx.x, d = threadIdx.x;
  if (d >= 96) return;
  int nb = go[g], ne = go[g+1];
  float acc = 0.f;
  for (int n = nb; n < ne; ++n) acc += h[(size_t)n*96 + d];
  pooled[g*96 + d] = acc;
}

// ---------------- cond MLP + concat + BN + fc ----------------

__global__ __launch_bounds__(64) void final_k(
    const float* __restrict__ cond, const float* __restrict__ pooled,
    const float* __restrict__ cW1, const float* __restrict__ cb1,
    const float* __restrict__ cg, const float* __restrict__ cbeta,
    const float* __restrict__ cmean, const float* __restrict__ cvar,
    const float* __restrict__ cW2, const float* __restrict__ cb2,
    const float* __restrict__ bn_g, const float* __restrict__ bn_b,
    const float* __restrict__ bn_mean, const float* __restrict__ bn_var,
    const float* __restrict__ fcW, const float* __restrict__ fcb,
    float* __restrict__ out)
{
  int g = blockIdx.x, t = threadIdx.x;
  float cin[7];
  #pragma unroll
  for (int j = 0; j < 7; ++j) cin[j] = cond[g*7+j];
  float c1[5];
  #pragma unroll
  for (int i = 0; i < 5; ++i){
    float a = cb1[i];
    #pragma unroll
    for (int j = 0; j < 7; ++j) a = fmaf(cin[j], cW1[j*5+i], a);
    float s = cg[i] * rsqrtf(cvar[i] + BN_EPS);
    a = (a - cmean[i])*s + cbeta[i];
    c1[i] = a > 0.f ? a : 0.f;
  }
  float c2[5];
  #pragma unroll
  for (int i = 0; i < 5; ++i){
    float a = cb2[i];
    #pragma unroll
    for (int j = 0; j < 5; ++j) a = fmaf(c1[j], cW2[j*5+i], a);
    c2[i] = a > 0.f ? a : 0.f;
  }
  float acc = fcb[t];
  #pragma unroll
  for (int j = 0; j < 5; ++j){
    float s = bn_g[j] * rsqrtf(bn_var[j] + BN_EPS);
    float nb = (c2[j] - bn_mean[j])*s + bn_b[j];
    acc = fmaf(nb, fcW[j*64 + t], acc);
  }
  for (int j = 5; j < 101; ++j){
    float vj = pooled[g*96 + (j-5)];
    float s = bn_g[j] * rsqrtf(bn_var[j] + BN_EPS);
    float nb = (vj - bn_mean[j])*s + bn_b[j];
    acc = fmaf(nb, fcW[j*64 + t], acc);
  }
  out[g*64 + t] = acc;
}

// ---------------- launch ----------------

extern "C" void kernel_launch(void* const* d_in, const int* in_sizes, int n_in,
                              void* d_out, int out_size, void* d_ws, size_t ws_size,
                              hipStream_t stream)
{
  const float* x         = (const float*)d_in[0];
  const float* cond      = (const float*)d_in[1];
  const int*   ei        = (const int*)  d_in[2];
  const int*   batch     = (const int*)  d_in[3];
  const float* conv_W1   = (const float*)d_in[4];
  const float* conv_b1   = (const float*)d_in[5];
  const float* conv_g    = (const float*)d_in[6];
  const float* conv_beta = (const float*)d_in[7];
  const float* conv_mean = (const float*)d_in[8];
  const float* conv_var  = (const float*)d_in[9];
  const float* conv_W2   = (const float*)d_in[10];
  const float* conv_b2   = (const float*)d_in[11];
  const float* cW1       = (const float*)d_in[12];
  const float* cb1       = (const float*)d_in[13];
  const float* cg        = (const float*)d_in[14];
  const float* cbeta     = (const float*)d_in[15];
  const float* cmean     = (const float*)d_in[16];
  const float* cvar      = (const float*)d_in[17];
  const float* cW2       = (const float*)d_in[18];
  const float* cb2       = (const float*)d_in[19];
  const float* bn_g      = (const float*)d_in[20];
  const float* bn_b      = (const float*)d_in[21];
  const float* bn_mean   = (const float*)d_in[22];
  const float* bn_var    = (const float*)d_in[23];
  const float* fc_W      = (const float*)d_in[24];
  const float* fc_b      = (const float*)d_in[25];

  const int D = 96;
  int N = in_sizes[0] / D;
  int G = in_sizes[1] / 7;
  int E = in_sizes[2] / 2;
  const int* src = ei;
  const int* dst = ei + E;

  char* p = (char*)d_ws;
  auto carve = [&](size_t bytes)->void*{
    void* r = (void*)p; p += (bytes + 255) & ~(size_t)255; return r;
  };
  int*   off    = (int*)  carve((size_t)(N+1)*4);
  int*   cursor = (int*)  carve((size_t)N*4);
  int*   bsum   = (int*)  carve(256*4);
  int*   srcs   = (int*)  carve((size_t)E*4);
  int*   go     = (int*)  carve((size_t)(G+1)*4);
  float* pooled = (float*)carve((size_t)G*D*4);
  float* hA     = (float*)carve((size_t)N*D*4);
  float* hB     = (float*)carve((size_t)N*D*4);

  int gE = (E+255)/256, gN = (N+255)/256;

  hipMemsetAsync(off, 0, (size_t)(N+1)*4, stream);
  hist_k   <<<gE, 256, 0, stream>>>(dst, off, E);
  scan1_k  <<<gN, 256, 0, stream>>>(off, bsum, N);
  scan2_k  <<<1,  256, 0, stream>>>(bsum, gN);
  scan3_k  <<<gN, 256, 0, stream>>>(off, cursor, bsum, N, E);
  scatter_k<<<gE, 256, 0, stream>>>(src, dst, cursor, srcs, E);
  bounds_k <<<gN, 256, 0, stream>>>(batch, go, N, G);

  const float* hin = x;
  for (int l = 0; l < 3; ++l){
    agg_k<<<(N+7)/8, 256, 0, stream>>>(hin, hB, off, srcs, N);
    mlp_sw_k<<<(N+63)/64, 512, 0, stream>>>(hB, hA,
        conv_W1 + (size_t)l*D*D, conv_b1 + l*D,
        conv_g + l*D, conv_beta + l*D, conv_mean + l*D, conv_var + l*D,
        conv_W2 + (size_t)l*D*D, conv_b2 + l*D, N);
    hin = hA;
  }

  pool_k <<<G, 128, 0, stream>>>(hA, go, pooled);
  final_k<<<G, 64,  0, stream>>>(cond, pooled, cW1, cb1, cg, cbeta, cmean, cvar,
                                 cW2, cb2, bn_g, bn_b, bn_mean, bn_var,
                                 fc_W, fc_b, (float*)d_out);
}